// Round 8
// baseline (318.297 us; speedup 1.0000x reference)
//
#include <hip/hip_runtime.h>

#define N_NODES_C 100000
#define N_EDGES_C 1600000
#define D_C 128
#define N_CLASSES_C 10
#define POOL_BLOCKS_C 2048
#define NBUCKET 391      // ceil(100000 / 256) nodes per bucket = 256
#define BUCKET_CAP 4608  // mean 4096, sigma 64 -> +8 sigma headroom
#define BPAD 16          // ints per bucket counter (one 64B line each)
#define EPB 4096         // edges per phase-A block
#define NB_A ((N_EDGES_C + EPB - 1) / EPB)  // 391

using bf16x8 = __attribute__((ext_vector_type(8))) short;
using f32x4  = __attribute__((ext_vector_type(4))) float;

// ---------------- bf16 helpers ----------------
__device__ __forceinline__ unsigned int pack_bf2(float a, float b) {
    unsigned int ua = __float_as_uint(a);
    unsigned int ub = __float_as_uint(b);
    ua = (ua + 0x7FFFu + ((ua >> 16) & 1u)) >> 16;          // RNE, low half
    ub = (ub + 0x7FFFu + ((ub >> 16) & 1u)) & 0xFFFF0000u;  // RNE, high half
    return ua | ub;
}

// r = 8 bf16 (uint4); acc[k] += v * f32(r[k])
__device__ __forceinline__ void bf8_fma(uint4 r, float v, float* acc) {
    acc[0] = fmaf(v, __uint_as_float(r.x << 16), acc[0]);
    acc[1] = fmaf(v, __uint_as_float(r.x & 0xFFFF0000u), acc[1]);
    acc[2] = fmaf(v, __uint_as_float(r.y << 16), acc[2]);
    acc[3] = fmaf(v, __uint_as_float(r.y & 0xFFFF0000u), acc[3]);
    acc[4] = fmaf(v, __uint_as_float(r.z << 16), acc[4]);
    acc[5] = fmaf(v, __uint_as_float(r.z & 0xFFFF0000u), acc[5]);
    acc[6] = fmaf(v, __uint_as_float(r.w << 16), acc[6]);
    acc[7] = fmaf(v, __uint_as_float(r.w & 0xFFFF0000u), acc[7]);
}

__device__ __forceinline__ int edge_word(const int* __restrict__ ei, long long idx, int is64) {
    return is64 ? ei[2 * idx] : ei[idx];
}

// ---------------- detect int64 vs int32 + zero bucket counters ----------------
__global__ void detect_init_kernel(const int* __restrict__ ei, int* __restrict__ flag,
                                   int* __restrict__ bcnt) {
    int t = threadIdx.x;
    if (blockIdx.x == 0) {
        if (t < 64) {  // wave 0: int64 detection (odd words all zero => int64)
            int nz = 0;
            for (int i = t; i < 512; i += 64) nz |= ei[2 * i + 1];
            unsigned long long b = __ballot(nz != 0);
            if (t == 0) *flag = (b == 0ULL) ? 1 : 0;
        }
    } else {
        int i = (blockIdx.x - 1) * 256 + t;
        if (i < NBUCKET * BPAD) bcnt[i] = 0;
    }
}

// ---------------- phase A: block-level counting sort into buckets ----------
__global__ __launch_bounds__(512) void bucket_fill_kernel(
        const int* __restrict__ ei, const float* __restrict__ attr,
        const int* __restrict__ flag, int* __restrict__ bcnt, int2* __restrict__ bkt) {
    __shared__ int2 stage[EPB];
    __shared__ unsigned short sbin[EPB];
    __shared__ int hist[512];    // padded to 512, zero above NBUCKET
    __shared__ int lstart[512];  // exclusive prefix (frozen)
    __shared__ int cursor[NBUCKET];
    __shared__ int gbase[NBUCKET];

    const int t = threadIdx.x;
    const long long e0 = (long long)blockIdx.x * EPB;
    const int n = (N_EDGES_C - e0 < EPB) ? (int)(N_EDGES_C - e0) : EPB;
    const int is64 = *flag;

    hist[t] = 0;
    __syncthreads();

    int  myb[8];
    int2 myrec[8];
#pragma unroll
    for (int j = 0; j < 8; ++j) {
        int i = t + j * 512;
        myb[j] = -1;
        if (i < n) {
            long long e = e0 + i;
            int s = edge_word(ei, e, is64);
            int d = edge_word(ei, (long long)N_EDGES_C + e, is64);
            float a = attr[e];
            int b = d >> 8;
            myb[j] = b;
            myrec[j].x = s | ((d & 0xFF) << 17);
            myrec[j].y = __float_as_int(a);
            atomicAdd(&hist[b], 1);
        }
    }
    __syncthreads();

    const int myh = hist[t];
    lstart[t] = myh;
    __syncthreads();
    for (int off = 1; off < 512; off <<= 1) {
        int v = lstart[t];
        int add = (t >= off) ? lstart[t - off] : 0;
        __syncthreads();
        lstart[t] = v + add;
        __syncthreads();
    }
    int excl = lstart[t] - myh;
    if (t < NBUCKET) cursor[t] = excl;
    lstart[t] = excl;
    __syncthreads();

#pragma unroll
    for (int j = 0; j < 8; ++j) {
        if (myb[j] >= 0) {
            int slot = atomicAdd(&cursor[myb[j]], 1);
            stage[slot] = myrec[j];
            sbin[slot] = (unsigned short)myb[j];
        }
    }
    if (t < NBUCKET) {
        int k = myh;
        gbase[t] = k ? atomicAdd(&bcnt[t * BPAD], k) : 0;
    }
    __syncthreads();

    for (int i = t; i < n; i += 512) {
        int b = sbin[i];
        int local = gbase[b] + (i - lstart[b]);
        if (local < BUCKET_CAP)
            bkt[(long long)b * BUCKET_CAP + local] = stage[i];
    }
}

// ---------------- phase B: in-place sort bucket by dst; emit rowinfo + dinv --
__global__ __launch_bounds__(256) void bucket_sort_kernel(
        const int* __restrict__ bcnt, int2* __restrict__ bkt,
        int2* __restrict__ rowinfo, float* __restrict__ dinv) {
    __shared__ int2 recA[BUCKET_CAP];
    __shared__ int2 recB[BUCKET_CAP];
    __shared__ int hist[256], lstart[256], cursor[256];
    __shared__ float degs[256];

    const int b = blockIdx.x, t = threadIdx.x;
    int n = bcnt[b * BPAD];
    if (n > BUCKET_CAP) n = BUCKET_CAP;
    int2* win = bkt + (long long)b * BUCKET_CAP;

    hist[t] = 0;
    degs[t] = 0.f;
    __syncthreads();

    for (int i = t; i < n; i += 256) {
        int2 cv = win[i];
        recA[i] = cv;
        int d = (cv.x >> 17) & 0xFF;
        atomicAdd(&hist[d], 1);
        atomicAdd(&degs[d], __int_as_float(cv.y));
    }
    __syncthreads();

    const int myh = hist[t];
    lstart[t] = myh;
    __syncthreads();
    for (int off = 1; off < 256; off <<= 1) {
        int v = lstart[t];
        int add = (t >= off) ? lstart[t - off] : 0;
        __syncthreads();
        lstart[t] = v + add;
        __syncthreads();
    }
    int excl = lstart[t] - myh;
    cursor[t] = excl;
    lstart[t] = excl;
    __syncthreads();

    for (int i = t; i < n; i += 256) {
        int2 cv = recA[i];
        int d = (cv.x >> 17) & 0xFF;
        int slot = atomicAdd(&cursor[d], 1);
        int2 o;
        o.x = cv.x & 0x1FFFF;
        o.y = cv.y;
        recB[slot] = o;
    }
    __syncthreads();

    for (int i = t; i < n; i += 256) win[i] = recB[i];

    int node = b * 256 + t;
    if (node < N_NODES_C) {
        int2 ri;
        ri.x = b * BUCKET_CAP + lstart[t];
        ri.y = myh;
        rowinfo[node] = ri;
        dinv[node] = rsqrtf(1.0f + degs[t]);  // self-loop weight 1
    }
}

// ---------------- pack W into MFMA B-fragment order (once) ----------------
// Entry (n,s,l): 8 bf16 = W[s*32 + (l>>4)*8 + j][n*16 + (l&15)], j=0..7.
__global__ __launch_bounds__(256) void prep_w_kernel(const float* __restrict__ W1,
                                                     const float* __restrict__ W2,
                                                     unsigned short* __restrict__ Wp1,
                                                     unsigned short* __restrict__ Wp2) {
    const float* W = (blockIdx.x & 8) ? W2 : W1;
    unsigned short* Wp = (blockIdx.x & 8) ? Wp2 : Wp1;
    const int n = blockIdx.x & 7;
    const int t = threadIdx.x;
    const int s = t >> 6, l = t & 63;
    const int col = n * 16 + (l & 15);
    const int k0 = s * 32 + (l >> 4) * 8;
    float v[8];
#pragma unroll
    for (int j = 0; j < 8; ++j) v[j] = W[(k0 + j) * 128 + col];
    uint4 o;
    o.x = pack_bf2(v[0], v[1]);
    o.y = pack_bf2(v[2], v[3]);
    o.z = pack_bf2(v[4], v[5]);
    o.w = pack_bf2(v[6], v[7]);
    ((uint4*)Wp)[(n * 4 + s) * 64 + l] = o;
}

// ---------------- MFMA GEMM: H(bf16) = dinv[row] * (A @ W) ----------------
// AF32: A is f32 (X), converted to bf16 fragments in-register (fuses convert_x).
// Block = 4 waves x 32 rows = 128 rows, full N=128, full K=128 (4 K-steps).
template <bool AF32>
__global__ __launch_bounds__(256) void gemm_mfma(const void* __restrict__ A,
                                                 const unsigned short* __restrict__ Wp,
                                                 const float* __restrict__ dinv,
                                                 unsigned short* __restrict__ H,
                                                 int nrows) {
    __shared__ unsigned short Bl[2048 * 8];  // 32 KB packed B
    {
        const uint4* src = (const uint4*)Wp;
        uint4* dst = (uint4*)Bl;
        for (int i = threadIdx.x; i < 2048; i += 256) dst[i] = src[i];
    }
    __syncthreads();

    const int wid = threadIdx.x >> 6, lane = threadIdx.x & 63;
    const int rowA = lane & 15, kg = lane >> 4;
    const int r0 = blockIdx.x * 128 + wid * 32;

    bf16x8 afr[2][4];
#pragma unroll
    for (int m = 0; m < 2; ++m) {
        int row = r0 + m * 16 + rowA;
        if (row >= nrows) row = nrows - 1;  // clamp; stores guarded below
        if constexpr (AF32) {
            const float* xp = (const float*)A + (long long)row * D_C + kg * 8;
#pragma unroll
            for (int s = 0; s < 4; ++s) {
                float4 lo = *(const float4*)(xp + s * 32);
                float4 hi = *(const float4*)(xp + s * 32 + 4);
                uint4 pk;
                pk.x = pack_bf2(lo.x, lo.y);
                pk.y = pack_bf2(lo.z, lo.w);
                pk.z = pack_bf2(hi.x, hi.y);
                pk.w = pack_bf2(hi.z, hi.w);
                afr[m][s] = __builtin_bit_cast(bf16x8, pk);
            }
        } else {
            const unsigned short* xp = (const unsigned short*)A + (long long)row * D_C + kg * 8;
#pragma unroll
            for (int s = 0; s < 4; ++s) afr[m][s] = *(const bf16x8*)(xp + s * 32);
        }
    }

    f32x4 acc[2][8];
#pragma unroll
    for (int m = 0; m < 2; ++m)
#pragma unroll
        for (int n = 0; n < 8; ++n) acc[m][n] = (f32x4){0.f, 0.f, 0.f, 0.f};

#pragma unroll
    for (int n = 0; n < 8; ++n) {
#pragma unroll
        for (int s = 0; s < 4; ++s) {
            bf16x8 bfr = *(const bf16x8*)(Bl + ((n * 4 + s) * 64 + lane) * 8);
            acc[0][n] = __builtin_amdgcn_mfma_f32_16x16x32_bf16(afr[0][s], bfr, acc[0][n], 0, 0, 0);
            acc[1][n] = __builtin_amdgcn_mfma_f32_16x16x32_bf16(afr[1][s], bfr, acc[1][n], 0, 0, 0);
        }
    }

    // epilogue: D[row=(lane>>4)*4+q][col=lane&15] per 16x16 tile
    const int colb = lane & 15, rq = lane >> 4;
#pragma unroll
    for (int m = 0; m < 2; ++m) {
#pragma unroll
        for (int q = 0; q < 4; ++q) {
            int row = r0 + m * 16 + rq * 4 + q;
            if (row >= nrows) continue;
            float sc = dinv[row];
#pragma unroll
            for (int n = 0; n < 8; ++n) {
                unsigned int u = __float_as_uint(acc[m][n][q] * sc);
                u = (u + 0x7FFFu + ((u >> 16) & 1u)) >> 16;
                H[(long long)row * D_C + n * 16 + colb] = (unsigned short)u;
            }
        }
    }
}

// ---------------- agg helpers ----------------
__device__ __forceinline__ void agg_edges(const unsigned short* __restrict__ h,
                                          const int2* __restrict__ row,
                                          int j, int m, int sub, float* acc) {
    for (; j + 7 < m; j += 8) {
        int2 c0 = row[j + 0], c1 = row[j + 1], c2 = row[j + 2], c3 = row[j + 3];
        int2 c4 = row[j + 4], c5 = row[j + 5], c6 = row[j + 6], c7 = row[j + 7];
        uint4 r0 = *(const uint4*)(h + (long long)c0.x * D_C + sub * 8);
        uint4 r1 = *(const uint4*)(h + (long long)c1.x * D_C + sub * 8);
        uint4 r2 = *(const uint4*)(h + (long long)c2.x * D_C + sub * 8);
        uint4 r3 = *(const uint4*)(h + (long long)c3.x * D_C + sub * 8);
        uint4 r4 = *(const uint4*)(h + (long long)c4.x * D_C + sub * 8);
        uint4 r5 = *(const uint4*)(h + (long long)c5.x * D_C + sub * 8);
        uint4 r6 = *(const uint4*)(h + (long long)c6.x * D_C + sub * 8);
        uint4 r7 = *(const uint4*)(h + (long long)c7.x * D_C + sub * 8);
        bf8_fma(r0, __int_as_float(c0.y), acc);
        bf8_fma(r1, __int_as_float(c1.y), acc);
        bf8_fma(r2, __int_as_float(c2.y), acc);
        bf8_fma(r3, __int_as_float(c3.y), acc);
        bf8_fma(r4, __int_as_float(c4.y), acc);
        bf8_fma(r5, __int_as_float(c5.y), acc);
        bf8_fma(r6, __int_as_float(c6.y), acc);
        bf8_fma(r7, __int_as_float(c7.y), acc);
    }
    for (; j + 3 < m; j += 4) {
        int2 c0 = row[j + 0], c1 = row[j + 1], c2 = row[j + 2], c3 = row[j + 3];
        uint4 r0 = *(const uint4*)(h + (long long)c0.x * D_C + sub * 8);
        uint4 r1 = *(const uint4*)(h + (long long)c1.x * D_C + sub * 8);
        uint4 r2 = *(const uint4*)(h + (long long)c2.x * D_C + sub * 8);
        uint4 r3 = *(const uint4*)(h + (long long)c3.x * D_C + sub * 8);
        bf8_fma(r0, __int_as_float(c0.y), acc);
        bf8_fma(r1, __int_as_float(c1.y), acc);
        bf8_fma(r2, __int_as_float(c2.y), acc);
        bf8_fma(r3, __int_as_float(c3.y), acc);
    }
    for (; j < m; ++j) {
        int2 cv = row[j];
        uint4 r = *(const uint4*)(h + (long long)cv.x * D_C + sub * 8);
        bf8_fma(r, __int_as_float(cv.y), acc);
    }
}

__device__ __forceinline__ void finish_node(const float* acc, float di,
                                            float4 bA, float4 bB, float* o) {
    o[0] = fmaxf(fmaf(acc[0], di, bA.x), 0.f);
    o[1] = fmaxf(fmaf(acc[1], di, bA.y), 0.f);
    o[2] = fmaxf(fmaf(acc[2], di, bA.z), 0.f);
    o[3] = fmaxf(fmaf(acc[3], di, bA.w), 0.f);
    o[4] = fmaxf(fmaf(acc[4], di, bB.x), 0.f);
    o[5] = fmaxf(fmaf(acc[5], di, bB.y), 0.f);
    o[6] = fmaxf(fmaf(acc[6], di, bB.z), 0.f);
    o[7] = fmaxf(fmaf(acc[7], di, bB.w), 0.f);
}

// ---------------- Aggregation: 16 lanes per 2 nodes (dual pipeline) --------
// Each 16-lane group owns TWO consecutive nodes; the common loop runs both
// 8-deep gather pipelines -> 16 independent row loads in flight per group.
// out_i = relu(dinv_i * (sum_j attr_j * g[col_j] + g[i]) + b)
// MODE 0: write [N,128] bf16 (feeds GEMM2). MODE 1: fuse mean-pool partials.
template <int MODE>
__global__ __launch_bounds__(256) void agg_kernel(
        const unsigned short* __restrict__ h, const float* __restrict__ dinv,
        const int2* __restrict__ rowinfo, const int2* __restrict__ recs,
        const float* __restrict__ bias, void* __restrict__ out_v) {
    __shared__ float pool[128];
    if (MODE == 1) {
        if (threadIdx.x < 128) pool[threadIdx.x] = 0.f;
        __syncthreads();
    }
    const int g    = threadIdx.x >> 4;   // group in block 0..15
    const int sub  = threadIdx.x & 15;
    const int lane = threadIdx.x & 63;
    const int grp  = lane >> 4;

    const float4 bA4 = *(const float4*)(bias + sub * 8);
    const float4 bB4 = *(const float4*)(bias + sub * 8 + 4);
    float p[8] = {0.f, 0.f, 0.f, 0.f, 0.f, 0.f, 0.f, 0.f};

    for (int i0 = blockIdx.x * 32 + g * 2; i0 < N_NODES_C; i0 += gridDim.x * 32) {
        const int iA = i0, iB = i0 + 1;
        const bool hB = (iB < N_NODES_C);
        const float diA = dinv[iA];
        const int2 riA = rowinfo[iA];
        float diB = 0.f;
        int2 riB = riA;
        if (hB) { diB = dinv[iB]; riB = rowinfo[iB]; }
        const int2* rowA = recs + riA.x;
        const int2* rowB = recs + riB.x;
        const int mA = riA.y;
        const int mB = hB ? riB.y : 0;

        float accA[8] = {0.f, 0.f, 0.f, 0.f, 0.f, 0.f, 0.f, 0.f};
        float accB[8] = {0.f, 0.f, 0.f, 0.f, 0.f, 0.f, 0.f, 0.f};
        {   // self terms
            uint4 sA = *(const uint4*)(h + (long long)iA * D_C + sub * 8);
            bf8_fma(sA, 1.0f, accA);
            if (hB) {
                uint4 sB = *(const uint4*)(h + (long long)iB * D_C + sub * 8);
                bf8_fma(sB, 1.0f, accB);
            }
        }

        int j = 0;
        const int mMin = (mA < mB) ? mA : mB;
        for (; j + 7 < mMin; j += 8) {
            int2 a0 = rowA[j + 0], a1 = rowA[j + 1], a2 = rowA[j + 2], a3 = rowA[j + 3];
            int2 a4 = rowA[j + 4], a5 = rowA[j + 5], a6 = rowA[j + 6], a7 = rowA[j + 7];
            int2 b0 = rowB[j + 0], b1 = rowB[j + 1], b2 = rowB[j + 2], b3 = rowB[j + 3];
            int2 b4 = rowB[j + 4], b5 = rowB[j + 5], b6 = rowB[j + 6], b7 = rowB[j + 7];
            uint4 ra0 = *(const uint4*)(h + (long long)a0.x * D_C + sub * 8);
            uint4 ra1 = *(const uint4*)(h + (long long)a1.x * D_C + sub * 8);
            uint4 ra2 = *(const uint4*)(h + (long long)a2.x * D_C + sub * 8);
            uint4 ra3 = *(const uint4*)(h + (long long)a3.x * D_C + sub * 8);
            uint4 ra4 = *(const uint4*)(h + (long long)a4.x * D_C + sub * 8);
            uint4 ra5 = *(const uint4*)(h + (long long)a5.x * D_C + sub * 8);
            uint4 ra6 = *(const uint4*)(h + (long long)a6.x * D_C + sub * 8);
            uint4 ra7 = *(const uint4*)(h + (long long)a7.x * D_C + sub * 8);
            uint4 rb0 = *(const uint4*)(h + (long long)b0.x * D_C + sub * 8);
            uint4 rb1 = *(const uint4*)(h + (long long)b1.x * D_C + sub * 8);
            uint4 rb2 = *(const uint4*)(h + (long long)b2.x * D_C + sub * 8);
            uint4 rb3 = *(const uint4*)(h + (long long)b3.x * D_C + sub * 8);
            uint4 rb4 = *(const uint4*)(h + (long long)b4.x * D_C + sub * 8);
            uint4 rb5 = *(const uint4*)(h + (long long)b5.x * D_C + sub * 8);
            uint4 rb6 = *(const uint4*)(h + (long long)b6.x * D_C + sub * 8);
            uint4 rb7 = *(const uint4*)(h + (long long)b7.x * D_C + sub * 8);
            bf8_fma(ra0, __int_as_float(a0.y), accA);
            bf8_fma(ra1, __int_as_float(a1.y), accA);
            bf8_fma(ra2, __int_as_float(a2.y), accA);
            bf8_fma(ra3, __int_as_float(a3.y), accA);
            bf8_fma(ra4, __int_as_float(a4.y), accA);
            bf8_fma(ra5, __int_as_float(a5.y), accA);
            bf8_fma(ra6, __int_as_float(a6.y), accA);
            bf8_fma(ra7, __int_as_float(a7.y), accA);
            bf8_fma(rb0, __int_as_float(b0.y), accB);
            bf8_fma(rb1, __int_as_float(b1.y), accB);
            bf8_fma(rb2, __int_as_float(b2.y), accB);
            bf8_fma(rb3, __int_as_float(b3.y), accB);
            bf8_fma(rb4, __int_as_float(b4.y), accB);
            bf8_fma(rb5, __int_as_float(b5.y), accB);
            bf8_fma(rb6, __int_as_float(b6.y), accB);
            bf8_fma(rb7, __int_as_float(b7.y), accB);
        }
        agg_edges(h, rowA, j, mA, sub, accA);
        if (hB) agg_edges(h, rowB, j, mB, sub, accB);

        float oA[8], oB[8];
        finish_node(accA, diA, bA4, bB4, oA);
        if (hB) finish_node(accB, diB, bA4, bB4, oB);

        if (MODE == 0) {
            uint4 pk;
            pk.x = pack_bf2(oA[0], oA[1]);
            pk.y = pack_bf2(oA[2], oA[3]);
            pk.z = pack_bf2(oA[4], oA[5]);
            pk.w = pack_bf2(oA[6], oA[7]);
            *(uint4*)((unsigned short*)out_v + (long long)iA * D_C + sub * 8) = pk;
            if (hB) {
                uint4 pk2;
                pk2.x = pack_bf2(oB[0], oB[1]);
                pk2.y = pack_bf2(oB[2], oB[3]);
                pk2.z = pack_bf2(oB[4], oB[5]);
                pk2.w = pack_bf2(oB[6], oB[7]);
                *(uint4*)((unsigned short*)out_v + (long long)iB * D_C + sub * 8) = pk2;
            }
        } else {
#pragma unroll
            for (int k = 0; k < 8; ++k) p[k] += oA[k];
            if (hB) {
#pragma unroll
                for (int k = 0; k < 8; ++k) p[k] += oB[k];
            }
        }
    }

    if (MODE == 1) {
#pragma unroll
        for (int k = 0; k < 8; ++k) {
            p[k] += __shfl_xor(p[k], 16);
            p[k] += __shfl_xor(p[k], 32);
        }
        if (grp == 0) {
#pragma unroll
            for (int k = 0; k < 8; ++k) atomicAdd(&pool[sub * 8 + k], p[k]);
        }
        __syncthreads();
        if (threadIdx.x < 128)
            ((float*)out_v)[blockIdx.x * 128 + threadIdx.x] = pool[threadIdx.x];
    }
}

// ---------------- final: reduce partials, pooled mean @ Wm + bm ----------------
__global__ __launch_bounds__(1024) void final_kernel(const float* __restrict__ part,
                                                     const float* __restrict__ Wm,
                                                     const float* __restrict__ bm,
                                                     float* __restrict__ out) {
    __shared__ float red[8][128];
    __shared__ float pooled[128];
    int t = threadIdx.x;           // 1024 threads
    int f = t & 127, c = t >> 7;   // c in 0..7
    float s = 0.f;
    for (int b = c; b < POOL_BLOCKS_C; b += 8) s += part[b * 128 + f];
    red[c][f] = s;
    __syncthreads();
    if (t < 128) {
        float tot = 0.f;
#pragma unroll
        for (int cc = 0; cc < 8; ++cc) tot += red[cc][t];
        pooled[t] = tot / (float)N_NODES_C;
    }
    __syncthreads();
    if (t < N_CLASSES_C) {
        float o = bm[t];
        for (int ff = 0; ff < 128; ++ff) o = fmaf(pooled[ff], Wm[ff * N_CLASSES_C + t], o);
        out[t] = o;
    }
}

// ---------------- host launch ----------------
extern "C" void kernel_launch(void* const* d_in, const int* in_sizes, int n_in,
                              void* d_out, int out_size, void* d_ws, size_t ws_size,
                              hipStream_t stream) {
    const float* x    = (const float*)d_in[0];
    const int*   ei   = (const int*)d_in[1];
    const float* attr = (const float*)d_in[2];
    const float* W1   = (const float*)d_in[3];
    const float* b1   = (const float*)d_in[4];
    const float* W2   = (const float*)d_in[5];
    const float* b2   = (const float*)d_in[6];
    const float* Wm   = (const float*)d_in[7];
    const float* bm   = (const float*)d_in[8];
    float* out = (float*)d_out;

    // workspace layout (256B aligned), ~69 MB total
    char* ws = (char*)d_ws;
    size_t off = 0;
    auto alloc = [&](size_t bytes) -> char* {
        char* p = ws + off;
        off += (bytes + 255) & ~(size_t)255;
        return p;
    };
    int*            flag    = (int*)alloc(4);
    int*            bcnt    = (int*)alloc((size_t)NBUCKET * BPAD * 4);              // 25 KB
    int2*           rowinfo = (int2*)alloc((size_t)N_NODES_C * 8);                  // 800 KB
    float*          dinv    = (float*)alloc((size_t)N_NODES_C * 4);                 // 400 KB
    int2*           bkt     = (int2*)alloc((size_t)NBUCKET * BUCKET_CAP * 8);       // 14.4 MB (CSR)
    float*          part    = (float*)alloc((size_t)POOL_BLOCKS_C * 128 * 4);       // 1 MB
    unsigned short* Wp1     = (unsigned short*)alloc(2048 * 8 * 2);                 // 32 KB
    unsigned short* Wp2     = (unsigned short*)alloc(2048 * 8 * 2);                 // 32 KB
    unsigned short* hbuf    = (unsigned short*)alloc((size_t)N_NODES_C * D_C * 2);  // 25.6 MB
    unsigned short* hb2     = (unsigned short*)alloc((size_t)N_NODES_C * D_C * 2);  // 25.6 MB
    (void)ws_size;

    const int ntiles = (N_NODES_C + 127) / 128;      // 782
    const int agg_blocks = (N_NODES_C + 31) / 32;    // 3125 (2 nodes per 16-lane group)
    const int init_blocks = 1 + (NBUCKET * BPAD + 255) / 256;

    detect_init_kernel<<<init_blocks, 256, 0, stream>>>(ei, flag, bcnt);
    bucket_fill_kernel<<<NB_A, 512, 0, stream>>>(ei, attr, flag, bcnt, bkt);
    bucket_sort_kernel<<<NBUCKET, 256, 0, stream>>>(bcnt, bkt, rowinfo, dinv);
    prep_w_kernel<<<16, 256, 0, stream>>>(W1, W2, Wp1, Wp2);

    // layer 1 (X f32 -> bf16 fragments fused into GEMM)
    gemm_mfma<true><<<ntiles, 256, 0, stream>>>(x, Wp1, dinv, hbuf, N_NODES_C);
    agg_kernel<0><<<agg_blocks, 256, 0, stream>>>(hbuf, dinv, rowinfo, bkt, b1, hb2);
    // layer 2 (mean-pool fused into aggregation)
    gemm_mfma<false><<<ntiles, 256, 0, stream>>>(hb2, Wp2, dinv, hbuf, N_NODES_C);
    agg_kernel<1><<<POOL_BLOCKS_C, 256, 0, stream>>>(hbuf, dinv, rowinfo, bkt, b2, part);
    final_kernel<<<1, 1024, 0, stream>>>(part, Wm, bm, out);
}

// Round 9
// 274.716 us; speedup vs baseline: 1.1586x; 1.1586x over previous
//
#include <hip/hip_runtime.h>

#define N_NODES_C 100000
#define N_EDGES_C 1600000
#define D_C 128
#define N_CLASSES_C 10
#define POOL_BLOCKS_C 2048
#define NBUCKET 391      // ceil(100000 / 256) nodes per bucket = 256
#define BUCKET_CAP 4608  // mean 4096, sigma 64 -> +8 sigma headroom
#define BPAD 16          // ints per bucket counter (one 64B line each)
#define EPB 4096         // edges per phase-A block
#define NB_A ((N_EDGES_C + EPB - 1) / EPB)  // 391

using bf16x8 = __attribute__((ext_vector_type(8))) short;
using f32x4  = __attribute__((ext_vector_type(4))) float;

// ---------------- bf16 helpers ----------------
__device__ __forceinline__ unsigned int pack_bf2(float a, float b) {
    unsigned int ua = __float_as_uint(a);
    unsigned int ub = __float_as_uint(b);
    ua = (ua + 0x7FFFu + ((ua >> 16) & 1u)) >> 16;          // RNE, low half
    ub = (ub + 0x7FFFu + ((ub >> 16) & 1u)) & 0xFFFF0000u;  // RNE, high half
    return ua | ub;
}

// r = 8 bf16 (uint4); acc[k] += v * f32(r[k])
__device__ __forceinline__ void bf8_fma(uint4 r, float v, float* acc) {
    acc[0] = fmaf(v, __uint_as_float(r.x << 16), acc[0]);
    acc[1] = fmaf(v, __uint_as_float(r.x & 0xFFFF0000u), acc[1]);
    acc[2] = fmaf(v, __uint_as_float(r.y << 16), acc[2]);
    acc[3] = fmaf(v, __uint_as_float(r.y & 0xFFFF0000u), acc[3]);
    acc[4] = fmaf(v, __uint_as_float(r.z << 16), acc[4]);
    acc[5] = fmaf(v, __uint_as_float(r.z & 0xFFFF0000u), acc[5]);
    acc[6] = fmaf(v, __uint_as_float(r.w << 16), acc[6]);
    acc[7] = fmaf(v, __uint_as_float(r.w & 0xFFFF0000u), acc[7]);
}

__device__ __forceinline__ int edge_word(const int* __restrict__ ei, long long idx, int is64) {
    return is64 ? ei[2 * idx] : ei[idx];
}

// ---------------- detect int64 vs int32 + zero bucket counters ----------------
__global__ void detect_init_kernel(const int* __restrict__ ei, int* __restrict__ flag,
                                   int* __restrict__ bcnt) {
    int t = threadIdx.x;
    if (blockIdx.x == 0) {
        if (t < 64) {  // wave 0: int64 detection (odd words all zero => int64)
            int nz = 0;
            for (int i = t; i < 512; i += 64) nz |= ei[2 * i + 1];
            unsigned long long b = __ballot(nz != 0);
            if (t == 0) *flag = (b == 0ULL) ? 1 : 0;
        }
    } else {
        int i = (blockIdx.x - 1) * 256 + t;
        if (i < NBUCKET * BPAD) bcnt[i] = 0;
    }
}

// ---------------- phase A: block-level counting sort into buckets ----------
__global__ __launch_bounds__(512) void bucket_fill_kernel(
        const int* __restrict__ ei, const float* __restrict__ attr,
        const int* __restrict__ flag, int* __restrict__ bcnt, int2* __restrict__ bkt) {
    __shared__ int2 stage[EPB];
    __shared__ unsigned short sbin[EPB];
    __shared__ int hist[512];    // padded to 512, zero above NBUCKET
    __shared__ int lstart[512];  // exclusive prefix (frozen)
    __shared__ int cursor[NBUCKET];
    __shared__ int gbase[NBUCKET];

    const int t = threadIdx.x;
    const long long e0 = (long long)blockIdx.x * EPB;
    const int n = (N_EDGES_C - e0 < EPB) ? (int)(N_EDGES_C - e0) : EPB;
    const int is64 = *flag;

    hist[t] = 0;
    __syncthreads();

    int  myb[8];
    int2 myrec[8];
#pragma unroll
    for (int j = 0; j < 8; ++j) {
        int i = t + j * 512;
        myb[j] = -1;
        if (i < n) {
            long long e = e0 + i;
            int s = edge_word(ei, e, is64);
            int d = edge_word(ei, (long long)N_EDGES_C + e, is64);
            float a = attr[e];
            int b = d >> 8;
            myb[j] = b;
            myrec[j].x = s | ((d & 0xFF) << 17);
            myrec[j].y = __float_as_int(a);
            atomicAdd(&hist[b], 1);
        }
    }
    __syncthreads();

    const int myh = hist[t];
    lstart[t] = myh;
    __syncthreads();
    for (int off = 1; off < 512; off <<= 1) {
        int v = lstart[t];
        int add = (t >= off) ? lstart[t - off] : 0;
        __syncthreads();
        lstart[t] = v + add;
        __syncthreads();
    }
    int excl = lstart[t] - myh;
    if (t < NBUCKET) cursor[t] = excl;
    lstart[t] = excl;
    __syncthreads();

#pragma unroll
    for (int j = 0; j < 8; ++j) {
        if (myb[j] >= 0) {
            int slot = atomicAdd(&cursor[myb[j]], 1);
            stage[slot] = myrec[j];
            sbin[slot] = (unsigned short)myb[j];
        }
    }
    if (t < NBUCKET) {
        int k = myh;
        gbase[t] = k ? atomicAdd(&bcnt[t * BPAD], k) : 0;
    }
    __syncthreads();

    for (int i = t; i < n; i += 512) {
        int b = sbin[i];
        int local = gbase[b] + (i - lstart[b]);
        if (local < BUCKET_CAP)
            bkt[(long long)b * BUCKET_CAP + local] = stage[i];
    }
}

// ---------------- phase B: in-place sort bucket by dst; emit rowinfo + dinv --
__global__ __launch_bounds__(256) void bucket_sort_kernel(
        const int* __restrict__ bcnt, int2* __restrict__ bkt,
        int2* __restrict__ rowinfo, float* __restrict__ dinv) {
    __shared__ int2 recA[BUCKET_CAP];
    __shared__ int2 recB[BUCKET_CAP];
    __shared__ int hist[256], lstart[256], cursor[256];
    __shared__ float degs[256];

    const int b = blockIdx.x, t = threadIdx.x;
    int n = bcnt[b * BPAD];
    if (n > BUCKET_CAP) n = BUCKET_CAP;
    int2* win = bkt + (long long)b * BUCKET_CAP;

    hist[t] = 0;
    degs[t] = 0.f;
    __syncthreads();

    for (int i = t; i < n; i += 256) {
        int2 cv = win[i];
        recA[i] = cv;
        int d = (cv.x >> 17) & 0xFF;
        atomicAdd(&hist[d], 1);
        atomicAdd(&degs[d], __int_as_float(cv.y));
    }
    __syncthreads();

    const int myh = hist[t];
    lstart[t] = myh;
    __syncthreads();
    for (int off = 1; off < 256; off <<= 1) {
        int v = lstart[t];
        int add = (t >= off) ? lstart[t - off] : 0;
        __syncthreads();
        lstart[t] = v + add;
        __syncthreads();
    }
    int excl = lstart[t] - myh;
    cursor[t] = excl;
    lstart[t] = excl;
    __syncthreads();

    for (int i = t; i < n; i += 256) {
        int2 cv = recA[i];
        int d = (cv.x >> 17) & 0xFF;
        int slot = atomicAdd(&cursor[d], 1);
        int2 o;
        o.x = cv.x & 0x1FFFF;
        o.y = cv.y;
        recB[slot] = o;
    }
    __syncthreads();

    for (int i = t; i < n; i += 256) win[i] = recB[i];

    int node = b * 256 + t;
    if (node < N_NODES_C) {
        int2 ri;
        ri.x = b * BUCKET_CAP + lstart[t];
        ri.y = myh;
        rowinfo[node] = ri;
        dinv[node] = rsqrtf(1.0f + degs[t]);  // self-loop weight 1
    }
}

// ---------------- pack W into MFMA B-fragment order (once) ----------------
// Entry (n,s,l): 8 bf16 = W[s*32 + (l>>4)*8 + j][n*16 + (l&15)], j=0..7.
__global__ __launch_bounds__(256) void prep_w_kernel(const float* __restrict__ W1,
                                                     const float* __restrict__ W2,
                                                     unsigned short* __restrict__ Wp1,
                                                     unsigned short* __restrict__ Wp2) {
    const float* W = (blockIdx.x & 8) ? W2 : W1;
    unsigned short* Wp = (blockIdx.x & 8) ? Wp2 : Wp1;
    const int n = blockIdx.x & 7;
    const int t = threadIdx.x;
    const int s = t >> 6, l = t & 63;
    const int col = n * 16 + (l & 15);
    const int k0 = s * 32 + (l >> 4) * 8;
    float v[8];
#pragma unroll
    for (int j = 0; j < 8; ++j) v[j] = W[(k0 + j) * 128 + col];
    uint4 o;
    o.x = pack_bf2(v[0], v[1]);
    o.y = pack_bf2(v[2], v[3]);
    o.z = pack_bf2(v[4], v[5]);
    o.w = pack_bf2(v[6], v[7]);
    ((uint4*)Wp)[(n * 4 + s) * 64 + l] = o;
}

// ---------------- MFMA GEMM: H(bf16) = dinv[row] * (A @ W) ----------------
// AF32: A is f32 (X), converted to bf16 fragments in-register (fuses convert_x).
// Block = 4 waves x 32 rows = 128 rows, full N=128, full K=128 (4 K-steps).
template <bool AF32>
__global__ __launch_bounds__(256) void gemm_mfma(const void* __restrict__ A,
                                                 const unsigned short* __restrict__ Wp,
                                                 const float* __restrict__ dinv,
                                                 unsigned short* __restrict__ H,
                                                 int nrows) {
    __shared__ unsigned short Bl[2048 * 8];  // 32 KB packed B
    {
        const uint4* src = (const uint4*)Wp;
        uint4* dst = (uint4*)Bl;
        for (int i = threadIdx.x; i < 2048; i += 256) dst[i] = src[i];
    }
    __syncthreads();

    const int wid = threadIdx.x >> 6, lane = threadIdx.x & 63;
    const int rowA = lane & 15, kg = lane >> 4;
    const int r0 = blockIdx.x * 128 + wid * 32;

    bf16x8 afr[2][4];
#pragma unroll
    for (int m = 0; m < 2; ++m) {
        int row = r0 + m * 16 + rowA;
        if (row >= nrows) row = nrows - 1;  // clamp; stores guarded below
        if constexpr (AF32) {
            const float* xp = (const float*)A + (long long)row * D_C + kg * 8;
#pragma unroll
            for (int s = 0; s < 4; ++s) {
                float4 lo = *(const float4*)(xp + s * 32);
                float4 hi = *(const float4*)(xp + s * 32 + 4);
                uint4 pk;
                pk.x = pack_bf2(lo.x, lo.y);
                pk.y = pack_bf2(lo.z, lo.w);
                pk.z = pack_bf2(hi.x, hi.y);
                pk.w = pack_bf2(hi.z, hi.w);
                afr[m][s] = __builtin_bit_cast(bf16x8, pk);
            }
        } else {
            const unsigned short* xp = (const unsigned short*)A + (long long)row * D_C + kg * 8;
#pragma unroll
            for (int s = 0; s < 4; ++s) afr[m][s] = *(const bf16x8*)(xp + s * 32);
        }
    }

    f32x4 acc[2][8];
#pragma unroll
    for (int m = 0; m < 2; ++m)
#pragma unroll
        for (int n = 0; n < 8; ++n) acc[m][n] = (f32x4){0.f, 0.f, 0.f, 0.f};

#pragma unroll
    for (int n = 0; n < 8; ++n) {
#pragma unroll
        for (int s = 0; s < 4; ++s) {
            bf16x8 bfr = *(const bf16x8*)(Bl + ((n * 4 + s) * 64 + lane) * 8);
            acc[0][n] = __builtin_amdgcn_mfma_f32_16x16x32_bf16(afr[0][s], bfr, acc[0][n], 0, 0, 0);
            acc[1][n] = __builtin_amdgcn_mfma_f32_16x16x32_bf16(afr[1][s], bfr, acc[1][n], 0, 0, 0);
        }
    }

    // epilogue: D[row=(lane>>4)*4+q][col=lane&15] per 16x16 tile
    const int colb = lane & 15, rq = lane >> 4;
#pragma unroll
    for (int m = 0; m < 2; ++m) {
#pragma unroll
        for (int q = 0; q < 4; ++q) {
            int row = r0 + m * 16 + rq * 4 + q;
            if (row >= nrows) continue;
            float sc = dinv[row];
#pragma unroll
            for (int n = 0; n < 8; ++n) {
                unsigned int u = __float_as_uint(acc[m][n][q] * sc);
                u = (u + 0x7FFFu + ((u >> 16) & 1u)) >> 16;
                H[(long long)row * D_C + n * 16 + colb] = (unsigned short)u;
            }
        }
    }
}

// ---------------- Aggregation: 16 lanes per node, dense dst-sorted CSR -----
// Round-7 structure (VGPR 56, 8-deep pipeline): confirmed-best ILP/TLP point.
// out_i = relu(dinv_i * (sum_j attr_j * g[col_j] + g[i]) + b)
// MODE 0: write [N,128] bf16 (feeds GEMM2). MODE 1: fuse mean-pool partials.
template <int MODE>
__global__ __launch_bounds__(256) void agg_kernel(
        const unsigned short* __restrict__ h, const float* __restrict__ dinv,
        const int2* __restrict__ rowinfo, const int2* __restrict__ recs,
        const float* __restrict__ bias, void* __restrict__ out_v) {
    __shared__ float pool[128];
    if (MODE == 1) {
        if (threadIdx.x < 128) pool[threadIdx.x] = 0.f;
        __syncthreads();
    }
    const int g    = threadIdx.x >> 4;   // group in block 0..15
    const int sub  = threadIdx.x & 15;
    const int lane = threadIdx.x & 63;
    const int grp  = lane >> 4;

    const float4 bA = *(const float4*)(bias + sub * 8);
    const float4 bB = *(const float4*)(bias + sub * 8 + 4);
    float p[8] = {0.f, 0.f, 0.f, 0.f, 0.f, 0.f, 0.f, 0.f};

    for (int i = blockIdx.x * 16 + g; i < N_NODES_C; i += gridDim.x * 16) {
        const float di = dinv[i];
        const int2 ri = rowinfo[i];
        const int2* row = recs + ri.x;
        const int m = ri.y;

        float acc[8] = {0.f, 0.f, 0.f, 0.f, 0.f, 0.f, 0.f, 0.f};
        {   // self term: + g[i]
            uint4 r = *(const uint4*)(h + (long long)i * D_C + sub * 8);
            bf8_fma(r, 1.0f, acc);
        }
        int j = 0;
        for (; j + 7 < m; j += 8) {
            int2 c0 = row[j + 0], c1 = row[j + 1], c2 = row[j + 2], c3 = row[j + 3];
            int2 c4 = row[j + 4], c5 = row[j + 5], c6 = row[j + 6], c7 = row[j + 7];
            uint4 r0 = *(const uint4*)(h + (long long)c0.x * D_C + sub * 8);
            uint4 r1 = *(const uint4*)(h + (long long)c1.x * D_C + sub * 8);
            uint4 r2 = *(const uint4*)(h + (long long)c2.x * D_C + sub * 8);
            uint4 r3 = *(const uint4*)(h + (long long)c3.x * D_C + sub * 8);
            uint4 r4 = *(const uint4*)(h + (long long)c4.x * D_C + sub * 8);
            uint4 r5 = *(const uint4*)(h + (long long)c5.x * D_C + sub * 8);
            uint4 r6 = *(const uint4*)(h + (long long)c6.x * D_C + sub * 8);
            uint4 r7 = *(const uint4*)(h + (long long)c7.x * D_C + sub * 8);
            bf8_fma(r0, __int_as_float(c0.y), acc);
            bf8_fma(r1, __int_as_float(c1.y), acc);
            bf8_fma(r2, __int_as_float(c2.y), acc);
            bf8_fma(r3, __int_as_float(c3.y), acc);
            bf8_fma(r4, __int_as_float(c4.y), acc);
            bf8_fma(r5, __int_as_float(c5.y), acc);
            bf8_fma(r6, __int_as_float(c6.y), acc);
            bf8_fma(r7, __int_as_float(c7.y), acc);
        }
        for (; j + 3 < m; j += 4) {
            int2 c0 = row[j + 0], c1 = row[j + 1], c2 = row[j + 2], c3 = row[j + 3];
            uint4 r0 = *(const uint4*)(h + (long long)c0.x * D_C + sub * 8);
            uint4 r1 = *(const uint4*)(h + (long long)c1.x * D_C + sub * 8);
            uint4 r2 = *(const uint4*)(h + (long long)c2.x * D_C + sub * 8);
            uint4 r3 = *(const uint4*)(h + (long long)c3.x * D_C + sub * 8);
            bf8_fma(r0, __int_as_float(c0.y), acc);
            bf8_fma(r1, __int_as_float(c1.y), acc);
            bf8_fma(r2, __int_as_float(c2.y), acc);
            bf8_fma(r3, __int_as_float(c3.y), acc);
        }
        for (; j < m; ++j) {
            int2 cv = row[j];
            uint4 r = *(const uint4*)(h + (long long)cv.x * D_C + sub * 8);
            bf8_fma(r, __int_as_float(cv.y), acc);
        }

        float o[8];
        o[0] = fmaxf(fmaf(acc[0], di, bA.x), 0.f);
        o[1] = fmaxf(fmaf(acc[1], di, bA.y), 0.f);
        o[2] = fmaxf(fmaf(acc[2], di, bA.z), 0.f);
        o[3] = fmaxf(fmaf(acc[3], di, bA.w), 0.f);
        o[4] = fmaxf(fmaf(acc[4], di, bB.x), 0.f);
        o[5] = fmaxf(fmaf(acc[5], di, bB.y), 0.f);
        o[6] = fmaxf(fmaf(acc[6], di, bB.z), 0.f);
        o[7] = fmaxf(fmaf(acc[7], di, bB.w), 0.f);

        if (MODE == 0) {
            uint4 pk;
            pk.x = pack_bf2(o[0], o[1]);
            pk.y = pack_bf2(o[2], o[3]);
            pk.z = pack_bf2(o[4], o[5]);
            pk.w = pack_bf2(o[6], o[7]);
            *(uint4*)((unsigned short*)out_v + (long long)i * D_C + sub * 8) = pk;
        } else {
#pragma unroll
            for (int k = 0; k < 8; ++k) p[k] += o[k];
        }
    }

    if (MODE == 1) {
#pragma unroll
        for (int k = 0; k < 8; ++k) {
            p[k] += __shfl_xor(p[k], 16);
            p[k] += __shfl_xor(p[k], 32);
        }
        if (grp == 0) {
#pragma unroll
            for (int k = 0; k < 8; ++k) atomicAdd(&pool[sub * 8 + k], p[k]);
        }
        __syncthreads();
        if (threadIdx.x < 128)
            ((float*)out_v)[blockIdx.x * 128 + threadIdx.x] = pool[threadIdx.x];
    }
}

// ---------------- final: reduce partials, pooled mean @ Wm + bm ----------------
__global__ __launch_bounds__(1024) void final_kernel(const float* __restrict__ part,
                                                     const float* __restrict__ Wm,
                                                     const float* __restrict__ bm,
                                                     float* __restrict__ out) {
    __shared__ float red[8][128];
    __shared__ float pooled[128];
    int t = threadIdx.x;           // 1024 threads
    int f = t & 127, c = t >> 7;   // c in 0..7
    float s = 0.f;
    for (int b = c; b < POOL_BLOCKS_C; b += 8) s += part[b * 128 + f];
    red[c][f] = s;
    __syncthreads();
    if (t < 128) {
        float tot = 0.f;
#pragma unroll
        for (int cc = 0; cc < 8; ++cc) tot += red[cc][t];
        pooled[t] = tot / (float)N_NODES_C;
    }
    __syncthreads();
    if (t < N_CLASSES_C) {
        float o = bm[t];
        for (int ff = 0; ff < 128; ++ff) o = fmaf(pooled[ff], Wm[ff * N_CLASSES_C + t], o);
        out[t] = o;
    }
}

// ---------------- host launch ----------------
extern "C" void kernel_launch(void* const* d_in, const int* in_sizes, int n_in,
                              void* d_out, int out_size, void* d_ws, size_t ws_size,
                              hipStream_t stream) {
    const float* x    = (const float*)d_in[0];
    const int*   ei   = (const int*)d_in[1];
    const float* attr = (const float*)d_in[2];
    const float* W1   = (const float*)d_in[3];
    const float* b1   = (const float*)d_in[4];
    const float* W2   = (const float*)d_in[5];
    const float* b2   = (const float*)d_in[6];
    const float* Wm   = (const float*)d_in[7];
    const float* bm   = (const float*)d_in[8];
    float* out = (float*)d_out;

    // workspace layout (256B aligned), ~69 MB total
    char* ws = (char*)d_ws;
    size_t off = 0;
    auto alloc = [&](size_t bytes) -> char* {
        char* p = ws + off;
        off += (bytes + 255) & ~(size_t)255;
        return p;
    };
    int*            flag    = (int*)alloc(4);
    int*            bcnt    = (int*)alloc((size_t)NBUCKET * BPAD * 4);              // 25 KB
    int2*           rowinfo = (int2*)alloc((size_t)N_NODES_C * 8);                  // 800 KB
    float*          dinv    = (float*)alloc((size_t)N_NODES_C * 4);                 // 400 KB
    int2*           bkt     = (int2*)alloc((size_t)NBUCKET * BUCKET_CAP * 8);       // 14.4 MB (CSR)
    float*          part    = (float*)alloc((size_t)POOL_BLOCKS_C * 128 * 4);       // 1 MB
    unsigned short* Wp1     = (unsigned short*)alloc(2048 * 8 * 2);                 // 32 KB
    unsigned short* Wp2     = (unsigned short*)alloc(2048 * 8 * 2);                 // 32 KB
    unsigned short* hbuf    = (unsigned short*)alloc((size_t)N_NODES_C * D_C * 2);  // 25.6 MB
    unsigned short* hb2     = (unsigned short*)alloc((size_t)N_NODES_C * D_C * 2);  // 25.6 MB
    (void)ws_size;

    const int ntiles = (N_NODES_C + 127) / 128;    // 782
    const int agg_blocks = (N_NODES_C + 15) / 16;  // 6250 (one node per 16-lane group)
    const int init_blocks = 1 + (NBUCKET * BPAD + 255) / 256;

    detect_init_kernel<<<init_blocks, 256, 0, stream>>>(ei, flag, bcnt);
    bucket_fill_kernel<<<NB_A, 512, 0, stream>>>(ei, attr, flag, bcnt, bkt);
    bucket_sort_kernel<<<NBUCKET, 256, 0, stream>>>(bcnt, bkt, rowinfo, dinv);
    prep_w_kernel<<<16, 256, 0, stream>>>(W1, W2, Wp1, Wp2);

    // layer 1 (X f32 -> bf16 fragments fused into GEMM)
    gemm_mfma<true><<<ntiles, 256, 0, stream>>>(x, Wp1, dinv, hbuf, N_NODES_C);
    agg_kernel<0><<<agg_blocks, 256, 0, stream>>>(hbuf, dinv, rowinfo, bkt, b1, hb2);
    // layer 2 (mean-pool fused into aggregation)
    gemm_mfma<false><<<ntiles, 256, 0, stream>>>(hb2, Wp2, dinv, hbuf, N_NODES_C);
    agg_kernel<1><<<POOL_BLOCKS_C, 256, 0, stream>>>(hbuf, dinv, rowinfo, bkt, b2, part);
    final_kernel<<<1, 1024, 0, stream>>>(part, Wm, bm, out);
}

// Round 10
// 217.495 us; speedup vs baseline: 1.4635x; 1.2631x over previous
//
#include <hip/hip_runtime.h>

#define N_NODES_C 100000
#define N_EDGES_C 1600000
#define D_C 128
#define N_CLASSES_C 10
#define POOL_BLOCKS_C 2048
#define POOL2_C 128      // after stage-1 reduction
#define NBUCKET 391      // ceil(100000 / 256) nodes per bucket = 256
#define BUCKET_CAP 4608  // mean 4096, sigma 64 -> +8 sigma headroom
#define BPAD 16          // ints per bucket counter (one 64B line each)
#define EPB 4096         // edges per phase-A block
#define NB_A ((N_EDGES_C + EPB - 1) / EPB)  // 391

using bf16x8 = __attribute__((ext_vector_type(8))) short;
using f32x4  = __attribute__((ext_vector_type(4))) float;

// ---------------- bf16 helpers ----------------
__device__ __forceinline__ unsigned int pack_bf2(float a, float b) {
    unsigned int ua = __float_as_uint(a);
    unsigned int ub = __float_as_uint(b);
    ua = (ua + 0x7FFFu + ((ua >> 16) & 1u)) >> 16;          // RNE, low half
    ub = (ub + 0x7FFFu + ((ub >> 16) & 1u)) & 0xFFFF0000u;  // RNE, high half
    return ua | ub;
}

// r = 8 bf16 (uint4); acc[k] += v * f32(r[k])
__device__ __forceinline__ void bf8_fma(uint4 r, float v, float* acc) {
    acc[0] = fmaf(v, __uint_as_float(r.x << 16), acc[0]);
    acc[1] = fmaf(v, __uint_as_float(r.x & 0xFFFF0000u), acc[1]);
    acc[2] = fmaf(v, __uint_as_float(r.y << 16), acc[2]);
    acc[3] = fmaf(v, __uint_as_float(r.y & 0xFFFF0000u), acc[3]);
    acc[4] = fmaf(v, __uint_as_float(r.z << 16), acc[4]);
    acc[5] = fmaf(v, __uint_as_float(r.z & 0xFFFF0000u), acc[5]);
    acc[6] = fmaf(v, __uint_as_float(r.w << 16), acc[6]);
    acc[7] = fmaf(v, __uint_as_float(r.w & 0xFFFF0000u), acc[7]);
}

__device__ __forceinline__ int edge_word(const int* __restrict__ ei, long long idx, int is64) {
    return is64 ? ei[2 * idx] : ei[idx];
}

// ---------------- detect int64 vs int32 + zero bucket counters ----------------
__global__ void detect_init_kernel(const int* __restrict__ ei, int* __restrict__ flag,
                                   int* __restrict__ bcnt) {
    int t = threadIdx.x;
    if (blockIdx.x == 0) {
        if (t < 64) {  // wave 0: int64 detection (odd words all zero => int64)
            int nz = 0;
            for (int i = t; i < 512; i += 64) nz |= ei[2 * i + 1];
            unsigned long long b = __ballot(nz != 0);
            if (t == 0) *flag = (b == 0ULL) ? 1 : 0;
        }
    } else {
        int i = (blockIdx.x - 1) * 256 + t;
        if (i < NBUCKET * BPAD) bcnt[i] = 0;
    }
}

// ---------------- phase A: block-level counting sort into buckets ----------
__global__ __launch_bounds__(512) void bucket_fill_kernel(
        const int* __restrict__ ei, const float* __restrict__ attr,
        const int* __restrict__ flag, int* __restrict__ bcnt, int2* __restrict__ bkt) {
    __shared__ int2 stage[EPB];
    __shared__ unsigned short sbin[EPB];
    __shared__ int hist[512];    // padded to 512, zero above NBUCKET
    __shared__ int lstart[512];  // exclusive prefix (frozen)
    __shared__ int cursor[NBUCKET];
    __shared__ int gbase[NBUCKET];

    const int t = threadIdx.x;
    const long long e0 = (long long)blockIdx.x * EPB;
    const int n = (N_EDGES_C - e0 < EPB) ? (int)(N_EDGES_C - e0) : EPB;
    const int is64 = *flag;

    hist[t] = 0;
    __syncthreads();

    int  myb[8];
    int2 myrec[8];
#pragma unroll
    for (int j = 0; j < 8; ++j) {
        int i = t + j * 512;
        myb[j] = -1;
        if (i < n) {
            long long e = e0 + i;
            int s = edge_word(ei, e, is64);
            int d = edge_word(ei, (long long)N_EDGES_C + e, is64);
            float a = attr[e];
            int b = d >> 8;
            myb[j] = b;
            myrec[j].x = s | ((d & 0xFF) << 17);
            myrec[j].y = __float_as_int(a);
            atomicAdd(&hist[b], 1);
        }
    }
    __syncthreads();

    const int myh = hist[t];
    lstart[t] = myh;
    __syncthreads();
    for (int off = 1; off < 512; off <<= 1) {
        int v = lstart[t];
        int add = (t >= off) ? lstart[t - off] : 0;
        __syncthreads();
        lstart[t] = v + add;
        __syncthreads();
    }
    int excl = lstart[t] - myh;
    if (t < NBUCKET) cursor[t] = excl;
    lstart[t] = excl;
    __syncthreads();

#pragma unroll
    for (int j = 0; j < 8; ++j) {
        if (myb[j] >= 0) {
            int slot = atomicAdd(&cursor[myb[j]], 1);
            stage[slot] = myrec[j];
            sbin[slot] = (unsigned short)myb[j];
        }
    }
    if (t < NBUCKET) {
        int k = myh;
        gbase[t] = k ? atomicAdd(&bcnt[t * BPAD], k) : 0;
    }
    __syncthreads();

    for (int i = t; i < n; i += 512) {
        int b = sbin[i];
        int local = gbase[b] + (i - lstart[b]);
        if (local < BUCKET_CAP)
            bkt[(long long)b * BUCKET_CAP + local] = stage[i];
    }
}

// ---------------- phase B: in-place sort bucket by dst; emit rowinfo + dinv --
__global__ __launch_bounds__(256) void bucket_sort_kernel(
        const int* __restrict__ bcnt, int2* __restrict__ bkt,
        int2* __restrict__ rowinfo, float* __restrict__ dinv) {
    __shared__ int2 recA[BUCKET_CAP];
    __shared__ int2 recB[BUCKET_CAP];
    __shared__ int hist[256], lstart[256], cursor[256];
    __shared__ float degs[256];

    const int b = blockIdx.x, t = threadIdx.x;
    int n = bcnt[b * BPAD];
    if (n > BUCKET_CAP) n = BUCKET_CAP;
    int2* win = bkt + (long long)b * BUCKET_CAP;

    hist[t] = 0;
    degs[t] = 0.f;
    __syncthreads();

    for (int i = t; i < n; i += 256) {
        int2 cv = win[i];
        recA[i] = cv;
        int d = (cv.x >> 17) & 0xFF;
        atomicAdd(&hist[d], 1);
        atomicAdd(&degs[d], __int_as_float(cv.y));
    }
    __syncthreads();

    const int myh = hist[t];
    lstart[t] = myh;
    __syncthreads();
    for (int off = 1; off < 256; off <<= 1) {
        int v = lstart[t];
        int add = (t >= off) ? lstart[t - off] : 0;
        __syncthreads();
        lstart[t] = v + add;
        __syncthreads();
    }
    int excl = lstart[t] - myh;
    cursor[t] = excl;
    lstart[t] = excl;
    __syncthreads();

    for (int i = t; i < n; i += 256) {
        int2 cv = recA[i];
        int d = (cv.x >> 17) & 0xFF;
        int slot = atomicAdd(&cursor[d], 1);
        int2 o;
        o.x = cv.x & 0x1FFFF;
        o.y = cv.y;
        recB[slot] = o;
    }
    __syncthreads();

    for (int i = t; i < n; i += 256) win[i] = recB[i];

    int node = b * 256 + t;
    if (node < N_NODES_C) {
        int2 ri;
        ri.x = b * BUCKET_CAP + lstart[t];
        ri.y = myh;
        rowinfo[node] = ri;
        dinv[node] = rsqrtf(1.0f + degs[t]);  // self-loop weight 1
    }
}

// ---------------- pack W into MFMA B-fragment order (once) ----------------
// Entry (n,s,l): 8 bf16 = W[s*32 + (l>>4)*8 + j][n*16 + (l&15)], j=0..7.
__global__ __launch_bounds__(256) void prep_w_kernel(const float* __restrict__ W1,
                                                     const float* __restrict__ W2,
                                                     unsigned short* __restrict__ Wp1,
                                                     unsigned short* __restrict__ Wp2) {
    const float* W = (blockIdx.x & 8) ? W2 : W1;
    unsigned short* Wp = (blockIdx.x & 8) ? Wp2 : Wp1;
    const int n = blockIdx.x & 7;
    const int t = threadIdx.x;
    const int s = t >> 6, l = t & 63;
    const int col = n * 16 + (l & 15);
    const int k0 = s * 32 + (l >> 4) * 8;
    float v[8];
#pragma unroll
    for (int j = 0; j < 8; ++j) v[j] = W[(k0 + j) * 128 + col];
    uint4 o;
    o.x = pack_bf2(v[0], v[1]);
    o.y = pack_bf2(v[2], v[3]);
    o.z = pack_bf2(v[4], v[5]);
    o.w = pack_bf2(v[6], v[7]);
    ((uint4*)Wp)[(n * 4 + s) * 64 + l] = o;
}

// ---------------- MFMA GEMM: H(bf16) = dinv[row] * (A @ W) ----------------
// AF32: A is f32 (X), converted to bf16 fragments in-register (fuses convert_x).
// Block = 4 waves x 32 rows = 128 rows, full N=128, full K=128 (4 K-steps).
template <bool AF32>
__global__ __launch_bounds__(256) void gemm_mfma(const void* __restrict__ A,
                                                 const unsigned short* __restrict__ Wp,
                                                 const float* __restrict__ dinv,
                                                 unsigned short* __restrict__ H,
                                                 int nrows) {
    __shared__ unsigned short Bl[2048 * 8];  // 32 KB packed B
    {
        const uint4* src = (const uint4*)Wp;
        uint4* dst = (uint4*)Bl;
        for (int i = threadIdx.x; i < 2048; i += 256) dst[i] = src[i];
    }
    __syncthreads();

    const int wid = threadIdx.x >> 6, lane = threadIdx.x & 63;
    const int rowA = lane & 15, kg = lane >> 4;
    const int r0 = blockIdx.x * 128 + wid * 32;

    bf16x8 afr[2][4];
#pragma unroll
    for (int m = 0; m < 2; ++m) {
        int row = r0 + m * 16 + rowA;
        if (row >= nrows) row = nrows - 1;  // clamp; stores guarded below
        if constexpr (AF32) {
            const float* xp = (const float*)A + (long long)row * D_C + kg * 8;
#pragma unroll
            for (int s = 0; s < 4; ++s) {
                float4 lo = *(const float4*)(xp + s * 32);
                float4 hi = *(const float4*)(xp + s * 32 + 4);
                uint4 pk;
                pk.x = pack_bf2(lo.x, lo.y);
                pk.y = pack_bf2(lo.z, lo.w);
                pk.z = pack_bf2(hi.x, hi.y);
                pk.w = pack_bf2(hi.z, hi.w);
                afr[m][s] = __builtin_bit_cast(bf16x8, pk);
            }
        } else {
            const unsigned short* xp = (const unsigned short*)A + (long long)row * D_C + kg * 8;
#pragma unroll
            for (int s = 0; s < 4; ++s) afr[m][s] = *(const bf16x8*)(xp + s * 32);
        }
    }

    f32x4 acc[2][8];
#pragma unroll
    for (int m = 0; m < 2; ++m)
#pragma unroll
        for (int n = 0; n < 8; ++n) acc[m][n] = (f32x4){0.f, 0.f, 0.f, 0.f};

#pragma unroll
    for (int n = 0; n < 8; ++n) {
#pragma unroll
        for (int s = 0; s < 4; ++s) {
            bf16x8 bfr = *(const bf16x8*)(Bl + ((n * 4 + s) * 64 + lane) * 8);
            acc[0][n] = __builtin_amdgcn_mfma_f32_16x16x32_bf16(afr[0][s], bfr, acc[0][n], 0, 0, 0);
            acc[1][n] = __builtin_amdgcn_mfma_f32_16x16x32_bf16(afr[1][s], bfr, acc[1][n], 0, 0, 0);
        }
    }

    // epilogue: D[row=(lane>>4)*4+q][col=lane&15] per 16x16 tile
    const int colb = lane & 15, rq = lane >> 4;
#pragma unroll
    for (int m = 0; m < 2; ++m) {
#pragma unroll
        for (int q = 0; q < 4; ++q) {
            int row = r0 + m * 16 + rq * 4 + q;
            if (row >= nrows) continue;
            float sc = dinv[row];
#pragma unroll
            for (int n = 0; n < 8; ++n) {
                unsigned int u = __float_as_uint(acc[m][n][q] * sc);
                u = (u + 0x7FFFu + ((u >> 16) & 1u)) >> 16;
                H[(long long)row * D_C + n * 16 + colb] = (unsigned short)u;
            }
        }
    }
}

// ---------------- Aggregation: 16 lanes per node, dense dst-sorted CSR -----
// Round-7 structure (VGPR 56, 8-deep pipeline): confirmed-best ILP/TLP point.
// out_i = relu(dinv_i * (sum_j attr_j * g[col_j] + g[i]) + b)
// MODE 0: write [N,128] bf16 (feeds GEMM2). MODE 1: fuse mean-pool partials.
template <int MODE>
__global__ __launch_bounds__(256) void agg_kernel(
        const unsigned short* __restrict__ h, const float* __restrict__ dinv,
        const int2* __restrict__ rowinfo, const int2* __restrict__ recs,
        const float* __restrict__ bias, void* __restrict__ out_v) {
    __shared__ float pool[128];
    if (MODE == 1) {
        if (threadIdx.x < 128) pool[threadIdx.x] = 0.f;
        __syncthreads();
    }
    const int g    = threadIdx.x >> 4;   // group in block 0..15
    const int sub  = threadIdx.x & 15;
    const int lane = threadIdx.x & 63;
    const int grp  = lane >> 4;

    const float4 bA = *(const float4*)(bias + sub * 8);
    const float4 bB = *(const float4*)(bias + sub * 8 + 4);
    float p[8] = {0.f, 0.f, 0.f, 0.f, 0.f, 0.f, 0.f, 0.f};

    for (int i = blockIdx.x * 16 + g; i < N_NODES_C; i += gridDim.x * 16) {
        const float di = dinv[i];
        const int2 ri = rowinfo[i];
        const int2* row = recs + ri.x;
        const int m = ri.y;

        float acc[8] = {0.f, 0.f, 0.f, 0.f, 0.f, 0.f, 0.f, 0.f};
        {   // self term: + g[i]
            uint4 r = *(const uint4*)(h + (long long)i * D_C + sub * 8);
            bf8_fma(r, 1.0f, acc);
        }
        int j = 0;
        for (; j + 7 < m; j += 8) {
            int2 c0 = row[j + 0], c1 = row[j + 1], c2 = row[j + 2], c3 = row[j + 3];
            int2 c4 = row[j + 4], c5 = row[j + 5], c6 = row[j + 6], c7 = row[j + 7];
            uint4 r0 = *(const uint4*)(h + (long long)c0.x * D_C + sub * 8);
            uint4 r1 = *(const uint4*)(h + (long long)c1.x * D_C + sub * 8);
            uint4 r2 = *(const uint4*)(h + (long long)c2.x * D_C + sub * 8);
            uint4 r3 = *(const uint4*)(h + (long long)c3.x * D_C + sub * 8);
            uint4 r4 = *(const uint4*)(h + (long long)c4.x * D_C + sub * 8);
            uint4 r5 = *(const uint4*)(h + (long long)c5.x * D_C + sub * 8);
            uint4 r6 = *(const uint4*)(h + (long long)c6.x * D_C + sub * 8);
            uint4 r7 = *(const uint4*)(h + (long long)c7.x * D_C + sub * 8);
            bf8_fma(r0, __int_as_float(c0.y), acc);
            bf8_fma(r1, __int_as_float(c1.y), acc);
            bf8_fma(r2, __int_as_float(c2.y), acc);
            bf8_fma(r3, __int_as_float(c3.y), acc);
            bf8_fma(r4, __int_as_float(c4.y), acc);
            bf8_fma(r5, __int_as_float(c5.y), acc);
            bf8_fma(r6, __int_as_float(c6.y), acc);
            bf8_fma(r7, __int_as_float(c7.y), acc);
        }
        for (; j + 3 < m; j += 4) {
            int2 c0 = row[j + 0], c1 = row[j + 1], c2 = row[j + 2], c3 = row[j + 3];
            uint4 r0 = *(const uint4*)(h + (long long)c0.x * D_C + sub * 8);
            uint4 r1 = *(const uint4*)(h + (long long)c1.x * D_C + sub * 8);
            uint4 r2 = *(const uint4*)(h + (long long)c2.x * D_C + sub * 8);
            uint4 r3 = *(const uint4*)(h + (long long)c3.x * D_C + sub * 8);
            bf8_fma(r0, __int_as_float(c0.y), acc);
            bf8_fma(r1, __int_as_float(c1.y), acc);
            bf8_fma(r2, __int_as_float(c2.y), acc);
            bf8_fma(r3, __int_as_float(c3.y), acc);
        }
        for (; j < m; ++j) {
            int2 cv = row[j];
            uint4 r = *(const uint4*)(h + (long long)cv.x * D_C + sub * 8);
            bf8_fma(r, __int_as_float(cv.y), acc);
        }

        float o[8];
        o[0] = fmaxf(fmaf(acc[0], di, bA.x), 0.f);
        o[1] = fmaxf(fmaf(acc[1], di, bA.y), 0.f);
        o[2] = fmaxf(fmaf(acc[2], di, bA.z), 0.f);
        o[3] = fmaxf(fmaf(acc[3], di, bA.w), 0.f);
        o[4] = fmaxf(fmaf(acc[4], di, bB.x), 0.f);
        o[5] = fmaxf(fmaf(acc[5], di, bB.y), 0.f);
        o[6] = fmaxf(fmaf(acc[6], di, bB.z), 0.f);
        o[7] = fmaxf(fmaf(acc[7], di, bB.w), 0.f);

        if (MODE == 0) {
            uint4 pk;
            pk.x = pack_bf2(o[0], o[1]);
            pk.y = pack_bf2(o[2], o[3]);
            pk.z = pack_bf2(o[4], o[5]);
            pk.w = pack_bf2(o[6], o[7]);
            *(uint4*)((unsigned short*)out_v + (long long)i * D_C + sub * 8) = pk;
        } else {
#pragma unroll
            for (int k = 0; k < 8; ++k) p[k] += o[k];
        }
    }

    if (MODE == 1) {
#pragma unroll
        for (int k = 0; k < 8; ++k) {
            p[k] += __shfl_xor(p[k], 16);
            p[k] += __shfl_xor(p[k], 32);
        }
        if (grp == 0) {
#pragma unroll
            for (int k = 0; k < 8; ++k) atomicAdd(&pool[sub * 8 + k], p[k]);
        }
        __syncthreads();
        if (threadIdx.x < 128)
            ((float*)out_v)[blockIdx.x * 128 + threadIdx.x] = pool[threadIdx.x];
    }
}

// ---------------- stage-1 reduce: part[2048][128] -> part2[128][128] -------
// 128 blocks; block b sums 16 consecutive rows. Coalesced (thread->feature).
__global__ __launch_bounds__(256) void reduce_part_kernel(const float* __restrict__ part,
                                                          float* __restrict__ part2) {
    __shared__ float tmp[128];
    const int f = threadIdx.x & 127;
    const int half = threadIdx.x >> 7;  // 0..1
    const int r0 = blockIdx.x * 16 + half * 8;
    float s = 0.f;
#pragma unroll
    for (int r = 0; r < 8; ++r) s += part[(r0 + r) * 128 + f];
    if (half == 0) tmp[f] = s;
    __syncthreads();
    if (half == 1) part2[blockIdx.x * 128 + f] = tmp[f] + s;
}

// ---------------- final: reduce part2, pooled mean @ Wm + bm ----------------
__global__ __launch_bounds__(1024) void final_kernel(const float* __restrict__ part2,
                                                     const float* __restrict__ Wm,
                                                     const float* __restrict__ bm,
                                                     float* __restrict__ out) {
    __shared__ float red[8][128];
    __shared__ float pooled[128];
    int t = threadIdx.x;           // 1024 threads
    int f = t & 127, c = t >> 7;   // c in 0..7
    float s = 0.f;
    for (int b = c; b < POOL2_C; b += 8) s += part2[b * 128 + f];
    red[c][f] = s;
    __syncthreads();
    if (t < 128) {
        float tot = 0.f;
#pragma unroll
        for (int cc = 0; cc < 8; ++cc) tot += red[cc][t];
        pooled[t] = tot / (float)N_NODES_C;
    }
    __syncthreads();
    if (t < N_CLASSES_C) {
        float o = bm[t];
        for (int ff = 0; ff < 128; ++ff) o = fmaf(pooled[ff], Wm[ff * N_CLASSES_C + t], o);
        out[t] = o;
    }
}

// ---------------- host launch ----------------
extern "C" void kernel_launch(void* const* d_in, const int* in_sizes, int n_in,
                              void* d_out, int out_size, void* d_ws, size_t ws_size,
                              hipStream_t stream) {
    const float* x    = (const float*)d_in[0];
    const int*   ei   = (const int*)d_in[1];
    const float* attr = (const float*)d_in[2];
    const float* W1   = (const float*)d_in[3];
    const float* b1   = (const float*)d_in[4];
    const float* W2   = (const float*)d_in[5];
    const float* b2   = (const float*)d_in[6];
    const float* Wm   = (const float*)d_in[7];
    const float* bm   = (const float*)d_in[8];
    float* out = (float*)d_out;

    // workspace layout (256B aligned), ~69 MB total
    char* ws = (char*)d_ws;
    size_t off = 0;
    auto alloc = [&](size_t bytes) -> char* {
        char* p = ws + off;
        off += (bytes + 255) & ~(size_t)255;
        return p;
    };
    int*            flag    = (int*)alloc(4);
    int*            bcnt    = (int*)alloc((size_t)NBUCKET * BPAD * 4);              // 25 KB
    int2*           rowinfo = (int2*)alloc((size_t)N_NODES_C * 8);                  // 800 KB
    float*          dinv    = (float*)alloc((size_t)N_NODES_C * 4);                 // 400 KB
    int2*           bkt     = (int2*)alloc((size_t)NBUCKET * BUCKET_CAP * 8);       // 14.4 MB (CSR)
    float*          part    = (float*)alloc((size_t)POOL_BLOCKS_C * 128 * 4);       // 1 MB
    float*          part2   = (float*)alloc((size_t)POOL2_C * 128 * 4);             // 64 KB
    unsigned short* Wp1     = (unsigned short*)alloc(2048 * 8 * 2);                 // 32 KB
    unsigned short* Wp2     = (unsigned short*)alloc(2048 * 8 * 2);                 // 32 KB
    unsigned short* hbuf    = (unsigned short*)alloc((size_t)N_NODES_C * D_C * 2);  // 25.6 MB
    unsigned short* hb2     = (unsigned short*)alloc((size_t)N_NODES_C * D_C * 2);  // 25.6 MB
    (void)ws_size;

    const int ntiles = (N_NODES_C + 127) / 128;    // 782
    const int agg_blocks = (N_NODES_C + 15) / 16;  // 6250 (one node per 16-lane group)
    const int init_blocks = 1 + (NBUCKET * BPAD + 255) / 256;

    detect_init_kernel<<<init_blocks, 256, 0, stream>>>(ei, flag, bcnt);
    bucket_fill_kernel<<<NB_A, 512, 0, stream>>>(ei, attr, flag, bcnt, bkt);
    bucket_sort_kernel<<<NBUCKET, 256, 0, stream>>>(bcnt, bkt, rowinfo, dinv);
    prep_w_kernel<<<16, 256, 0, stream>>>(W1, W2, Wp1, Wp2);

    // layer 1 (X f32 -> bf16 fragments fused into GEMM)
    gemm_mfma<true><<<ntiles, 256, 0, stream>>>(x, Wp1, dinv, hbuf, N_NODES_C);
    agg_kernel<0><<<agg_blocks, 256, 0, stream>>>(hbuf, dinv, rowinfo, bkt, b1, hb2);
    // layer 2 (mean-pool fused into aggregation)
    gemm_mfma<false><<<ntiles, 256, 0, stream>>>(hb2, Wp2, dinv, hbuf, N_NODES_C);
    agg_kernel<1><<<POOL_BLOCKS_C, 256, 0, stream>>>(hbuf, dinv, rowinfo, bkt, b2, part);
    reduce_part_kernel<<<POOL2_C, 256, 0, stream>>>(part, part2);
    final_kernel<<<1, 1024, 0, stream>>>(part2, Wm, bm, out);
}